// Round 12
// baseline (204.168 us; speedup 1.0000x reference)
//
#include <hip/hip_runtime.h>

// HetConv: out = concat(spmm(row1,col1,val1,x), spmm(row2,col2,val2,x), axis=1)
// N=20000, E=320000 each, D=256, fp32 in/out. out = [20000, 512].
//
// Round 12: build = round 10 (proven). k4 reworked for XCD-local gathers:
//   xh stored SLICED: [4][NODES][64] bf16 (4 slices x 128 B per row).
//   k4 wave-unit = (joint row, slice); slice = blockIdx.x & 3 so each XCD
//   (blockIdx % 8 round-robin) touches ONE 2.56 MB slice plane -> L2-resident.
//   8 lanes per edge-slot (ushort8 = 16 B each), 8 slots in flight; each lane
//   loads its own (c,v) -> no per-edge cross-lane ops; one 24-op shfl_xor
//   butterfly per wave merges the 8 slot-groups; lanes 0-7 store 256 B fp32.

#define NODES 20000
#define D_FEAT 256
#define OUT_STRIDE (2 * D_FEAT)
#define NR (2 * NODES)
#define REP 8
#define CAP 64
#define NSLICE 4
#define SLICE_F 64           // bf16 features per slice
#define SPILL_CAP 16384

typedef float vfloat4 __attribute__((ext_vector_type(4)));
typedef int   vint2   __attribute__((ext_vector_type(2)));
typedef unsigned short vushort8 __attribute__((ext_vector_type(8)));

__device__ __forceinline__ unsigned short f2bf(float f) {
    unsigned u = __float_as_uint(f);
    unsigned r = u + 0x7FFFu + ((u >> 16) & 1u);   // RNE
    return (unsigned short)(r >> 16);
}
__device__ __forceinline__ float bf2f(unsigned short h) {
    return __uint_as_float((unsigned)h << 16);
}

// ---- k1a: replicated count + rank; x -> bf16 convert (sliced layout) ----

__global__ __launch_bounds__(256) void k1a_count(
    const int* __restrict__ row1, int E1,
    const int* __restrict__ row2, int E2,
    int* __restrict__ cnt,                 // [REP][NR]
    unsigned short* __restrict__ rankl,    // [Et]
    const float* __restrict__ x, unsigned short* __restrict__ xh,
    int edge_blocks, int conv_elems)
{
    if ((int)blockIdx.x < edge_blocks) {
        const int i = blockIdx.x * 256 + threadIdx.x;
        const int Et = E1 + E2;
        if (i >= Et) return;
        const int rj = (i < E1) ? row1[i] : (NODES + row2[i - E1]);
        const int rep = blockIdx.x & (REP - 1);    // ~XCD-local replica
        rankl[i] = (unsigned short)atomicAdd(&cnt[(size_t)rep * NR + rj], 1);
    } else {
        const int b = blockIdx.x - edge_blocks;
        const long base = ((long)b * 256 + threadIdx.x) * 8;
        if (base >= conv_elems) return;
        const float4 a = reinterpret_cast<const float4*>(x + base)[0];
        const float4 c = reinterpret_cast<const float4*>(x + base)[1];
        vushort8 h;
        h.s0 = f2bf(a.x); h.s1 = f2bf(a.y); h.s2 = f2bf(a.z); h.s3 = f2bf(a.w);
        h.s4 = f2bf(c.x); h.s5 = f2bf(c.y); h.s6 = f2bf(c.z); h.s7 = f2bf(c.w);
        // sliced layout: row = base/256, d0 = base%256 (8-aligned)
        const long row = base >> 8;
        const int  d0  = (int)(base & 255);
        const int  sl  = d0 >> 6;
        const int  within = d0 & 63;
        unsigned short* dst = xh + ((size_t)sl * NODES + row) * SLICE_F + within;
        *reinterpret_cast<vushort8*>(dst) = h;
    }
}

// ---- k1b: per-row replica scan -> bases + capped deg ----

__global__ __launch_bounds__(256) void k1b_bases(
    int* __restrict__ cnt, int* __restrict__ deg)
{
    const int row = blockIdx.x * 256 + threadIdx.x;
    if (row >= NR) return;
    int run = 0;
    #pragma unroll
    for (int r = 0; r < REP; ++r) {
        const int c = cnt[(size_t)r * NR + row];
        cnt[(size_t)r * NR + row] = run;       // exclusive base
        run += c;
    }
    deg[row] = min(run, CAP);
}

// ---- k1c: dense place (atomic-free) ----

__global__ __launch_bounds__(256) void k1c_place(
    const int* __restrict__ row1, const int* __restrict__ col1,
    const float* __restrict__ val1, int E1,
    const int* __restrict__ row2, const int* __restrict__ col2,
    const float* __restrict__ val2, int E2,
    const int* __restrict__ cnt,           // bases now
    const unsigned short* __restrict__ rankl,
    int2* __restrict__ pairs,              // [NR][CAP] dense prefix
    int* __restrict__ spill_cnt, int4* __restrict__ spill)
{
    const int i = blockIdx.x * 256 + threadIdx.x;
    const int Et = E1 + E2;
    if (i >= Et) return;
    int rj, c; float v;
    if (i < E1) { rj = row1[i];                 c = col1[i]; v = val1[i]; }
    else { const int e = i - E1; rj = NODES + row2[e]; c = col2[e]; v = val2[e]; }
    const int rep = blockIdx.x & (REP - 1);        // same mapping as k1a
    const int pos = cnt[(size_t)rep * NR + rj] + (int)rankl[i];
    if (pos < CAP) {
        pairs[(size_t)rj * CAP + pos] = make_int2(c, __float_as_int(v));
    } else {
        const int s = atomicAdd(spill_cnt, 1);
        if (s < SPILL_CAP)
            spill[s] = make_int4(rj, c, __float_as_int(v), 0);
    }
}

// ---- k4: SpMM, XCD-local sliced gather ----

__global__ __launch_bounds__(256) void k4_spmm(
    const unsigned short* __restrict__ xh, float* __restrict__ out,
    const int* __restrict__ deg, const int2* __restrict__ pairs,
    const int* __restrict__ spill_cnt, const int4* __restrict__ spill)
{
    const int wid  = threadIdx.x >> 6;
    const int lane = threadIdx.x & 63;
    const int slice  = blockIdx.x & (NSLICE - 1);   // == XCD % 4 (round-robin)
    const int rowgrp = blockIdx.x >> 2;
    const int rj = rowgrp * 4 + wid;
    if (rj >= NR) return;
    const int half = (rj >= NODES) ? 1 : 0;
    const int r = rj - half * NODES;

    const int es = lane >> 3;              // edge-slot group 0..7
    const int fo = lane & 7;               // feature sub-block 0..7 (8 bf16)
    const int dg = deg[rj];

    const unsigned short* xbase =
        xh + (size_t)slice * NODES * SLICE_F + fo * 8;

    float a0 = 0.f, a1 = 0.f, a2 = 0.f, a3 = 0.f;
    float a4 = 0.f, a5 = 0.f, a6 = 0.f, a7 = 0.f;

    for (int k = 0; k < dg; k += 8) {
        const int slot = k + es;
        int c = 0; float v = 0.f;
        if (slot < dg) {
            const vint2 p = __builtin_nontemporal_load(
                reinterpret_cast<const vint2*>(pairs) + (size_t)rj * CAP + slot);
            c = p.x; v = __int_as_float(p.y);
        }
        const vushort8 h = *reinterpret_cast<const vushort8*>(
            xbase + (size_t)c * SLICE_F);
        a0 += v * bf2f(h.s0); a1 += v * bf2f(h.s1);
        a2 += v * bf2f(h.s2); a3 += v * bf2f(h.s3);
        a4 += v * bf2f(h.s4); a5 += v * bf2f(h.s5);
        a6 += v * bf2f(h.s6); a7 += v * bf2f(h.s7);
    }

    // spill pass (normally 0 entries); only slot-group 0 accumulates
    const int sc = min(*spill_cnt, SPILL_CAP);
    for (int s = 0; s < sc; ++s) {
        const int4 sp = spill[s];
        if (sp.x == rj && es == 0) {
            const float sv = __int_as_float(sp.z);
            const vushort8 h = *reinterpret_cast<const vushort8*>(
                xbase + (size_t)sp.y * SLICE_F);
            a0 += sv * bf2f(h.s0); a1 += sv * bf2f(h.s1);
            a2 += sv * bf2f(h.s2); a3 += sv * bf2f(h.s3);
            a4 += sv * bf2f(h.s4); a5 += sv * bf2f(h.s5);
            a6 += sv * bf2f(h.s6); a7 += sv * bf2f(h.s7);
        }
    }

    // merge the 8 slot-groups (butterfly over lane strides 8,16,32)
    #pragma unroll
    for (int d = 8; d < 64; d <<= 1) {
        a0 += __shfl_xor(a0, d); a1 += __shfl_xor(a1, d);
        a2 += __shfl_xor(a2, d); a3 += __shfl_xor(a3, d);
        a4 += __shfl_xor(a4, d); a5 += __shfl_xor(a5, d);
        a6 += __shfl_xor(a6, d); a7 += __shfl_xor(a7, d);
    }

    if (es == 0) {   // lanes 0..7 store 32 B each = 256 B fp32 slice
        float* orow = out + (size_t)r * OUT_STRIDE + half * D_FEAT
                      + slice * SLICE_F + fo * 8;
        vfloat4 lo, hi2;
        lo.x = a0; lo.y = a1; lo.z = a2; lo.w = a3;
        hi2.x = a4; hi2.y = a5; hi2.z = a6; hi2.w = a7;
        __builtin_nontemporal_store(lo,  reinterpret_cast<vfloat4*>(orow));
        __builtin_nontemporal_store(hi2, reinterpret_cast<vfloat4*>(orow + 4));
    }
}

// ---- fallback (round-1 atomic path) ----

__global__ __launch_bounds__(256) void spmm_edge_atomic(
    const int* __restrict__ row, const int* __restrict__ col,
    const float* __restrict__ val, const float* __restrict__ x,
    float* __restrict__ out, int num_edges, int col_off)
{
    const int wave_in_block = threadIdx.x >> 6;
    const int lane = threadIdx.x & 63;
    const int e = blockIdx.x * 4 + wave_in_block;
    if (e >= num_edges) return;
    const int r = row[e];
    const int c = col[e];
    const float v = val[e];
    const float4 xv = reinterpret_cast<const float4*>(x + (size_t)c * D_FEAT)[lane];
    float* orow = out + (size_t)r * OUT_STRIDE + col_off + lane * 4;
    atomicAdd(orow + 0, v * xv.x);
    atomicAdd(orow + 1, v * xv.y);
    atomicAdd(orow + 2, v * xv.z);
    atomicAdd(orow + 3, v * xv.w);
}

extern "C" void kernel_launch(void* const* d_in, const int* in_sizes, int n_in,
                              void* d_out, int out_size, void* d_ws, size_t ws_size,
                              hipStream_t stream)
{
    const float* x    = (const float*)d_in[0];
    const int*   row1 = (const int*)d_in[1];
    const int*   col1 = (const int*)d_in[2];
    const float* val1 = (const float*)d_in[3];
    const int*   row2 = (const int*)d_in[4];
    const int*   col2 = (const int*)d_in[5];
    const float* val2 = (const float*)d_in[6];
    float* out = (float*)d_out;

    const int E1 = in_sizes[1];
    const int E2 = in_sizes[4];
    const int Et = E1 + E2;
    const int conv_elems = NODES * D_FEAT;

    // ws layout (int units):
    //   cnt       REP*NR       (zeroed)
    //   spill_cnt 1 (+pad 3)   (zeroed)
    //   deg       NR
    //   rankl     Et ushorts  = Et/2 ints
    //   spill     4*SPILL_CAP  (int4, 16B aligned)
    //   pairs     2*NR*CAP     (int2, 8B aligned)
    //   xh        conv_elems/2 (16B aligned), sliced [4][NODES][64]
    const size_t o_cnt   = 0;
    const size_t o_scnt  = o_cnt + (size_t)REP * NR;
    const size_t o_deg   = o_scnt + 4;
    const size_t o_rank  = o_deg + NR;
    const size_t o_spill = (o_rank + ((size_t)Et + 1) / 2 + 3) & ~(size_t)3;
    const size_t o_pairs = o_spill + 4 * (size_t)SPILL_CAP;
    const size_t o_xh    = (o_pairs + 2 * (size_t)NR * CAP + 3) & ~(size_t)3;
    const size_t need_ints = o_xh + (size_t)conv_elems / 2;

    if (ws_size < need_ints * sizeof(int) || (o_pairs & 1) || (o_xh & 3)) {
        (void)hipMemsetAsync(d_out, 0, (size_t)out_size * sizeof(float), stream);
        spmm_edge_atomic<<<dim3((E1 + 3) / 4), 256, 0, stream>>>(
            row1, col1, val1, x, out, E1, 0);
        spmm_edge_atomic<<<dim3((E2 + 3) / 4), 256, 0, stream>>>(
            row2, col2, val2, x, out, E2, D_FEAT);
        return;
    }

    int* w = (int*)d_ws;
    int*  cnt       = w + o_cnt;
    int*  spill_cnt = w + o_scnt;
    int*  deg       = w + o_deg;
    unsigned short* rankl = (unsigned short*)(w + o_rank);
    int4* spill     = (int4*)(w + o_spill);
    int2* pairs     = (int2*)(w + o_pairs);
    unsigned short* xh = (unsigned short*)(w + o_xh);

    // zero cnt + spill_cnt (~1.3 MB)
    (void)hipMemsetAsync(cnt, 0, (o_deg - o_cnt) * sizeof(int), stream);

    const int edge_blocks = (Et + 255) / 256;
    const int conv_blocks = (conv_elems + 256 * 8 - 1) / (256 * 8);
    k1a_count<<<dim3(edge_blocks + conv_blocks), 256, 0, stream>>>(
        row1, E1, row2, E2, cnt, rankl, x, xh, edge_blocks, conv_elems);
    k1b_bases<<<dim3((NR + 255) / 256), 256, 0, stream>>>(cnt, deg);
    k1c_place<<<dim3(edge_blocks), 256, 0, stream>>>(
        row1, col1, val1, E1, row2, col2, val2, E2,
        cnt, rankl, pairs, spill_cnt, spill);
    // 1D grid: blockIdx&3 = slice (XCD-aligned), 4 rows per block
    k4_spmm<<<dim3(NR), 256, 0, stream>>>(
        xh, out, deg, pairs, spill_cnt, spill);
}